// Round 14
// baseline (59.680 us; speedup 1.0000x reference)
//
#include <hip/hip_runtime.h>

// corr via MFMA band extraction + LDS-transposed coalesced stores + vector loads.
// out[b,di*9+(dj+4),h,w] = sum_c x[b,c,h,w] * y[b,c,refl(h+di-4),refl(w+dj)]
// A = Y_bf16[w'-tile, c], B = X_bf16[c, w-tile]; D[w',w] diagonals = dj.
// R14 = R12 skeleton (4 blocks/CU, 2 barriers, pstage-72) with the load side
// vectorized: Y = float4 interior + 2 halo scalars per thread-row; X staged in
// LDS (float4, no 4x wave duplication), B-frags via ds_read_b128.

#define HH   256
#define WW   256
#define CCH  64
#define KRAD 4
#define ND   81

#define WT   16
#define HT   16
#define WY   24
#define RSTRIDE 128             // 64c * 2B, XOR-swizzled 16B chunks
#define YRING 10
#define YSLOT (WY * RSTRIDE)    // 3072 B
#define XSLOT (WT * RSTRIDE)    // 2048 B
#define PSTRIDE 72              // 18 dwords: write banks <=2-way

typedef __attribute__((ext_vector_type(8))) short bf16x8;
typedef __attribute__((ext_vector_type(4))) float f32x4;

__device__ __forceinline__ int reflect(int v, int n) {
    v = v < 0 ? -v : v;
    return v >= n ? 2 * n - 2 - v : v;
}
__device__ __forceinline__ unsigned short f2bf(float f) {
    union { float f; unsigned u; } v; v.f = f;
    return (unsigned short)((v.u + 0x7fffu + ((v.u >> 16) & 1u)) >> 16);
}
__device__ __forceinline__ int mod10(int s) {   // s in [0, 30)
    if (s >= 20) s -= 20; else if (s >= 10) s -= 10;
    return s;
}

__global__ __launch_bounds__(256, 4) void corr_mfma_kernel(
    const float* __restrict__ x, const float* __restrict__ y,
    float* __restrict__ out)
{
    // 30720 (Y ring) + 4096 (X dbuf) + 5832 + 12 = 40660 B -> 4 blocks/CU
    __shared__ char lds[YRING * YSLOT + 2 * XSLOT + ND * PSTRIDE + 12];
    char* ylds   = lds;
    char* xlds   = lds + YRING * YSLOT;
    char* pstage = xlds + 2 * XSLOT;

    // XCD-chunked bijective swizzle: 1024 blocks = 8 XCDs * 128
    const int d  = blockIdx.x;
    const int v  = (d & 7) * 128 + (d >> 3);
    const int b  = v >> 8;
    const int by = (v >> 4) & 15;
    const int bx = v & 15;
    const int w0 = bx * WT;
    const int h0 = by * HT;

    const int t    = threadIdx.x;
    const int wid  = t >> 6;
    const int lane = t & 63;
    const int lq   = lane >> 4;      // 0..3
    const int ln   = lane & 15;      // 0..15

    const size_t plane = (size_t)HH * WW;
    const float* yb = y + (size_t)b * CCH * plane;
    const float* xb = x + (size_t)b * CCH * plane;

    // staging decodes
    const int yc  = t >> 2, ywc = t & 3;     // Y interior: c (0..63), w-chunk (0..3)
    const int yhc = t >> 3, yhk = t & 7;     // Y halo: c (0..31, +32), halo idx
    const int yph = (yhk < 4) ? yhk : yhk + 16;   // halo yp in {0..3, 20..23}
    const int xc  = t >> 2, xwc = t & 3;     // X: c (0..63), w-chunk (0..3)

    auto loadYi = [&](int L, f32x4& f4) {    // interior 16 w, always in-bounds
        int gh = reflect(h0 - KRAD + L, HH);
        f4 = *(const f32x4*)(yb + (size_t)yc * plane + (size_t)gh * WW + (w0 + ywc * 4));
    };
    auto loadYh = [&](int L, float& a, float& bb) {   // halo w, per-element reflect
        int gh = reflect(h0 - KRAD + L, HH);
        int gw = reflect(w0 - KRAD + yph, WW);
        const float* p = yb + (size_t)yhc * plane + (size_t)gh * WW + gw;
        a  = *p;
        bb = *(p + (size_t)32 * plane);
    };
    auto writeY = [&](int L, const f32x4& f4, float ha, float hb) {
        char* base = ylds + mod10(L) * YSLOT;
#pragma unroll
        for (int e = 0; e < 4; ++e) {
            int yp = 4 + ywc * 4 + e;
            char* p = base + yp * RSTRIDE
                    + ((((unsigned)(yc >> 3)) * 16) ^ (((unsigned)(yp & 7)) << 4))
                    + (yc & 7) * 2;
            *(unsigned short*)p = f2bf(f4[e]);
        }
        {
            char* p = base + yph * RSTRIDE
                    + ((((unsigned)(yhc >> 3)) * 16) ^ (((unsigned)(yph & 7)) << 4))
                    + (yhc & 7) * 2;
            *(unsigned short*)p = f2bf(ha);
            int c2 = yhc + 32;
            char* p2 = base + yph * RSTRIDE
                     + ((((unsigned)(c2 >> 3)) * 16) ^ (((unsigned)(yph & 7)) << 4))
                     + (c2 & 7) * 2;
            *(unsigned short*)p2 = f2bf(hb);
        }
    };
    auto loadX4 = [&](int hrow, f32x4& f4) {
        int gh = reflect(hrow, HH);
        f4 = *(const f32x4*)(xb + (size_t)xc * plane + (size_t)gh * WW + (w0 + xwc * 4));
    };
    auto writeX4 = [&](int buf, const f32x4& f4) {
        char* base = xlds + buf * XSLOT;
#pragma unroll
        for (int e = 0; e < 4; ++e) {
            int xp = xwc * 4 + e;
            char* p = base + xp * RSTRIDE
                    + ((((unsigned)(xc >> 3)) * 16) ^ (((unsigned)(xp & 7)) << 4))
                    + (xc & 7) * 2;
            *(unsigned short*)p = f2bf(f4[e]);
        }
    };

    f32x4 yi, yi2, xv4;
    float ha, hb, ha2, hb2;

    // ---- prologue: Y rows L=0..8 (2-deep pipelined); X row h0 -> buf 0 ----
    loadYi(0, yi); loadYh(0, ha, hb);
#pragma unroll 1
    for (int j = 0; j < 9; ++j) {
        if (j < 8) { loadYi(j + 1, yi2); loadYh(j + 1, ha2, hb2); }
        writeY(j, yi, ha, hb);
        yi = yi2; ha = ha2; hb = hb2;
    }
    loadX4(h0, xv4);
    writeX4(0, xv4);
    __syncthreads();

    const int mbase = lq * 4;
    const int prow  = t >> 4;        // readback: didx sub-row
    const int pcol  = t & 15;        // readback: w column
    const unsigned swl = ((unsigned)(ln & 7)) << 4;

    // ---- main loop over h ----
#pragma unroll 1
    for (int hh = 0; hh < HT; ++hh) {
        const int h   = h0 + hh;
        const int cur = hh & 1;

        // issue next-iteration global loads (consumed post-barrier-1)
        loadYi(hh + 9, yi); loadYh(hh + 9, ha, hb);
        loadX4(h + 1, xv4);

        // B fragments from X LDS buf[cur]
        const char* xrow = xlds + cur * XSLOT + ln * RSTRIDE;
        bf16x8 bf0 = *(const bf16x8*)(xrow + (((unsigned)(lq * 16)) ^ swl));
        bf16x8 bf1 = *(const bf16x8*)(xrow + (((unsigned)(64 + lq * 16)) ^ swl));

        // 18 (di,wt) units split across 4 waves: 5/5/4/4
        for (int u = wid; u < 18; u += 4) {
            const int di = u >> 1;
            const int wt = u & 1;
            const int slot = mod10(hh + di);
            const char* abase = ylds + slot * YSLOT + (wt * 16 + ln) * RSTRIDE;
            bf16x8 af0 = *(const bf16x8*)(abase + (((unsigned)(lq * 16)) ^ swl));
            bf16x8 af1 = *(const bf16x8*)(abase + (((unsigned)(64 + lq * 16)) ^ swl));
            f32x4 dacc = {0.f, 0.f, 0.f, 0.f};
            dacc = __builtin_amdgcn_mfma_f32_16x16x32_bf16(af0, bf0, dacc, 0, 0, 0);
            dacc = __builtin_amdgcn_mfma_f32_16x16x32_bf16(af1, bf1, dacc, 0, 0, 0);
            // transpose via LDS: pstage[didx][ln], didx = di*9 + (dj+4)
            char* psu = pstage + di * (9 * PSTRIDE) + ln * 4;
#pragma unroll
            for (int r = 0; r < 4; ++r) {
                const int vr = mbase + r - ln + (wt ? 16 : 0);   // dj+4
                if ((unsigned)vr <= 8u)
                    *(float*)(psu + vr * PSTRIDE) = dacc[r];
            }
        }

        // barrier 1: pstage writes visible; frag reads drained
        __builtin_amdgcn_sched_barrier(0);
        asm volatile("s_waitcnt lgkmcnt(0)" ::: "memory");
        __builtin_amdgcn_s_barrier();
        __builtin_amdgcn_sched_barrier(0);

        // stage next-iteration tiles during the readback phase
        writeY(hh + 9, yi, ha, hb);
        writeX4(cur ^ 1, xv4);

        // coalesced readback: 81 rows of 16 w (full 64B lines)
        {
            float* og = out + (size_t)b * ND * plane + (size_t)h * WW + (w0 + pcol);
#pragma unroll
            for (int p = 0; p < 6; ++p) {
                const int didx = p * 16 + prow;
                if (p < 5 || prow == 0) {
                    float vv = *(const float*)(pstage + didx * PSTRIDE + pcol * 4);
                    og[(size_t)didx * plane] = vv;
                }
            }
        }

        // barrier 2: readback + staging writes complete before next iter
        __builtin_amdgcn_sched_barrier(0);
        asm volatile("s_waitcnt lgkmcnt(0)" ::: "memory");
        __builtin_amdgcn_s_barrier();
        __builtin_amdgcn_sched_barrier(0);
    }
}

extern "C" void kernel_launch(void* const* d_in, const int* in_sizes, int n_in,
                              void* d_out, int out_size, void* d_ws, size_t ws_size,
                              hipStream_t stream) {
    const float* x = (const float*)d_in[0];
    const float* y = (const float*)d_in[1];
    float* out = (float*)d_out;

    dim3 grid(1024);   // 16 w-tiles * 16 h-tiles * 4 batch, XCD-swizzled in-kernel
    dim3 block(256);
    corr_mfma_kernel<<<grid, block, 0, stream>>>(x, y, out);
}